// Round 6
// baseline (18.960 us; speedup 1.0000x reference)
//
#include <hip/hip_runtime.h>
#include <hip/hip_fp16.h>
#include <math.h>

#define NB 128      // batches
#define TC 128      // subsampled points per batch
#define HALF 64     // output rows per block
#define DD 512      // feature dim
#define TSTR 16     // subsample stride (2048/128)
#define NTRIP 32
#define DSTH 130    // f16 dmat row stride

typedef __attribute__((ext_vector_type(8))) short bf16x8;
typedef __attribute__((ext_vector_type(4))) unsigned short u16x4;
typedef __attribute__((ext_vector_type(4))) float f32x4;

__device__ __forceinline__ unsigned short f2bf(float f) {
  unsigned int u = __float_as_uint(f);   // RNE bf16
  return (unsigned short)((u + 0x7fffu + ((u >> 16) & 1u)) >> 16);
}

// grid = 256: block (s = blk>>7, b = blk&127) -> rows [s*64,s*64+64) x cols
// [0,128). 512 threads = 8 waves. Whole bf16 X staged once into swizzled LDS
// with PERFECTLY COALESCED loads: each global_load_dwordx4 covers 1 KB
// contiguous (lane l -> row_base + l*16B) = 16 cache lines, vs 64 before.
__global__ __launch_bounds__(512, 2) void topo_half(
    const float* __restrict__ latent,   // [128][2048][512]
    const float* __restrict__ thr,      // [1]
    const int*   __restrict__ trip,     // [128][32][3]
    float* __restrict__ ws_psum,        // [256]
    float* __restrict__ ws_edge)        // [128*32*3]
{
  const int blk  = blockIdx.x;
  const int s    = blk >> 7;          // row-half
  const int b    = blk & 127;         // batch
  const int tid  = threadIdx.x;
  const int l    = tid & 63;
  const int wid  = tid >> 6;          // 0..7

  __shared__ unsigned short xs[TC * DD];   // 128 KB, XOR-swizzled
  __shared__ __half dmat[HALF][DSTH];      // 16.6 KB
  __shared__ float sqn[TC];
  __shared__ float wred[8];

  const float* xb = latent + (size_t)b * (2048 * 512);

  // ---- staging: wave w owns rows w*16..w*16+15; per row two 1-KB instrs ----
#define LOAD_GROUP(dst, base_row)                                           \
  _Pragma("unroll") for (int k = 0; k < 4; ++k) {                           \
    const float* rp = xb + (size_t)((base_row) + k) * (TSTR * DD) + (l << 2); \
    dst[2 * k]     = *reinterpret_cast<const float4*>(rp);                  \
    dst[2 * k + 1] = *reinterpret_cast<const float4*>(rp + 256);            \
  }

#define PROC_GROUP(srcv, base_row)                                          \
  _Pragma("unroll") for (int k = 0; k < 4; ++k) {                           \
    const int r = (base_row) + k;                                           \
    float4 h0 = srcv[2 * k], h1 = srcv[2 * k + 1];                          \
    u16x4 w0, w1;                                                           \
    w0[0]=f2bf(h0.x); w0[1]=f2bf(h0.y); w0[2]=f2bf(h0.z); w0[3]=f2bf(h0.w); \
    w1[0]=f2bf(h1.x); w1[1]=f2bf(h1.y); w1[2]=f2bf(h1.z); w1[3]=f2bf(h1.w); \
    const int sw = (r & 7) << 3;                                            \
    *reinterpret_cast<u16x4*>(&xs[(r * DD + (l << 2)) ^ sw])       = w0;    \
    *reinterpret_cast<u16x4*>(&xs[(r * DD + 256 + (l << 2)) ^ sw]) = w1;    \
    float ss = h0.x*h0.x + h0.y*h0.y + h0.z*h0.z + h0.w*h0.w                \
             + h1.x*h1.x + h1.y*h1.y + h1.z*h1.z + h1.w*h1.w;               \
    ss += __shfl_xor(ss, 1, 64);  ss += __shfl_xor(ss, 2, 64);              \
    ss += __shfl_xor(ss, 4, 64);  ss += __shfl_xor(ss, 8, 64);              \
    ss += __shfl_xor(ss, 16, 64); ss += __shfl_xor(ss, 32, 64);             \
    if (l == 0) sqn[r] = ss;                                                \
  }

  {
    const int rb = wid * 16;
    float4 bufA[8], bufB[8];
    LOAD_GROUP(bufA, rb);
    LOAD_GROUP(bufB, rb + 4);     // 16 loads in flight before first use
    PROC_GROUP(bufA, rb);
    LOAD_GROUP(bufA, rb + 8);
    PROC_GROUP(bufB, rb + 4);
    LOAD_GROUP(bufB, rb + 12);
    PROC_GROUP(bufA, rb + 8);
    PROC_GROUP(bufB, rb + 12);
  }
  __syncthreads();

  // ---- MFMA: wave (wr,wc) -> local 32x32 tile; no barriers needed ----
  const int wr = wid >> 2, wc = wid & 3;
  const int ar0 = s * HALF + wr * 32 + (l & 15);   // global A rows
  const int br0 = wc * 32 + (l & 15);              // global B rows (cols)
  const int kk0 = (l >> 4) << 3;

  f32x4 acc[2][2];
#pragma unroll
  for (int i = 0; i < 2; ++i)
#pragma unroll
    for (int j = 0; j < 2; ++j)
#pragma unroll
      for (int r = 0; r < 4; ++r) acc[i][j][r] = 0.f;

  const int swA = (ar0 & 7) << 3;   // (ar0+16) has same low-3 row bits
  const int swB = (br0 & 7) << 3;
#pragma unroll
  for (int t = 0; t < 8; ++t) {
#pragma unroll
    for (int sub = 0; sub < 2; ++sub) {
      const int kc = t * 64 + sub * 32 + kk0;
      bf16x8 A0 = *reinterpret_cast<const bf16x8*>(&xs[(ar0 * DD + kc) ^ swA]);
      bf16x8 A1 = *reinterpret_cast<const bf16x8*>(&xs[((ar0 + 16) * DD + kc) ^ swA]);
      bf16x8 B0 = *reinterpret_cast<const bf16x8*>(&xs[(br0 * DD + kc) ^ swB]);
      bf16x8 B1 = *reinterpret_cast<const bf16x8*>(&xs[((br0 + 16) * DD + kc) ^ swB]);
      acc[0][0] = __builtin_amdgcn_mfma_f32_16x16x32_bf16(A0, B0, acc[0][0], 0, 0, 0);
      acc[0][1] = __builtin_amdgcn_mfma_f32_16x16x32_bf16(A0, B1, acc[0][1], 0, 0, 0);
      acc[1][0] = __builtin_amdgcn_mfma_f32_16x16x32_bf16(A1, B0, acc[1][0], 0, 0, 0);
      acc[1][1] = __builtin_amdgcn_mfma_f32_16x16x32_bf16(A1, B1, acc[1][1], 0, 0, 0);
    }
  }

  // ---- epilogue: d, sigmoid-sum, f16 dmat (C/D map: col=lane&15, row=(lane>>4)*4+reg) ----
  const int rbase = (l >> 4) << 2;
  const int cidx  = l & 15;
  const float thv = fabsf(thr[0]) + 0.1f;
  float psum = 0.f;
#pragma unroll
  for (int fr = 0; fr < 2; ++fr)
#pragma unroll
    for (int fc = 0; fc < 2; ++fc)
#pragma unroll
      for (int reg = 0; reg < 4; ++reg) {
        int growL = wr * 32 + fr * 16 + rbase + reg;   // local row 0..63
        int grow  = s * HALF + growL;                  // global row
        int gcol  = wc * 32 + fc * 16 + cidx;
        float d = 0.f;
        if (grow != gcol) {
          float g  = acc[fr][fc][reg];
          float sq = fmaxf(sqn[grow] + sqn[gcol] - 2.f * g, 0.f);
          d = sqrtf(sq);
          psum += 1.f / (1.f + __expf(d - thv));
        }
        dmat[growL][gcol] = __float2half(d);
      }

#pragma unroll
  for (int off = 32; off; off >>= 1) psum += __shfl_down(psum, off, 64);
  if (l == 0) wred[wid] = psum;
  __syncthreads();   // fences dmat for edge gather

  if (wid == 0) {
    if (l < NTRIP) {
      const int* tp = trip + ((size_t)b * NTRIP + l) * 3;
      const int i0 = tp[0], i1 = tp[1], i2 = tp[2];
      const size_t ebase = ((size_t)b * NTRIP + l) * 3;
      int ps[3] = {i0, i0, i1};
      int qs[3] = {i1, i2, i2};
#pragma unroll
      for (int e = 0; e < 3; ++e) {
        int p = ps[e], q = qs[e];
        int mx = p > q ? p : q, mn = p > q ? q : p;
        if ((mx >> 6) == s)   // this block owns the edge
          ws_edge[ebase + e] = (mx == mn) ? 0.f
                             : __half2float(dmat[mx - s * HALF][mn]);
      }
    }
    if (l == 0) {
      float conn = 0.f;
#pragma unroll
      for (int w = 0; w < 8; ++w) conn += wred[w];
      ws_psum[blk] = conn;
    }
  }
}

// Grand final: sum 256 psum partials + 4096 triplet hole terms.
__global__ __launch_bounds__(1024) void topo_final(
    const float* __restrict__ ws_psum,
    const float* __restrict__ ws_edge,
    float* __restrict__ out)
{
  const int t    = threadIdx.x;
  const int lane = t & 63;
  const int wid  = t >> 6;

  float ps = (t < 2 * NB) ? ws_psum[t] : 0.f;
  float hs = 0.f;
#pragma unroll
  for (int k = 0; k < 4; ++k) {
    int id = t + 1024 * k;            // 0..4095 triplet slots
    float e0 = ws_edge[id * 3 + 0];
    float e1 = ws_edge[id * 3 + 1];
    float e2 = ws_edge[id * 3 + 2];
    float m  = (e0 + e1 + e2) * (1.f / 3.f);
    float d0 = e0 - m, d1 = e1 - m, d2 = e2 - m;
    float v  = (d0 * d0 + d1 * d1 + d2 * d2) * 0.5f;   // ddof=1
    hs += __expf(-v);
  }

#pragma unroll
  for (int off = 32; off; off >>= 1) {
    ps += __shfl_down(ps, off, 64);
    hs += __shfl_down(hs, off, 64);
  }
  __shared__ float rp[16], rh[16];
  if (lane == 0) { rp[wid] = ps; rh[wid] = hs; }
  __syncthreads();
  if (t == 0) {
    float Ps = 0.f, Hs = 0.f;
#pragma unroll
    for (int w = 0; w < 16; ++w) { Ps += rp[w]; Hs += rh[w]; }
    out[0] = 1.f - Ps / (16256.f * NB) + 0.5f * (Hs / (NB * NTRIP));
  }
}

extern "C" void kernel_launch(void* const* d_in, const int* in_sizes, int n_in,
                              void* d_out, int out_size, void* d_ws, size_t ws_size,
                              hipStream_t stream) {
  const float* latent = (const float*)d_in[0];
  const float* thr    = (const float*)d_in[1];
  const int*   trip   = (const int*)d_in[2];

  float* ws_psum = (float*)d_ws;              // 256 floats
  float* ws_edge = ws_psum + 2 * NB;          // 12288 floats

  topo_half<<<2 * NB, 512, 0, stream>>>(latent, thr, trip, ws_psum, ws_edge);
  topo_final<<<1, 1024, 0, stream>>>(ws_psum, ws_edge, (float*)d_out);
}